// Round 5
// baseline (332.120 us; speedup 1.0000x reference)
//
#include <hip/hip_runtime.h>
#include <hip/hip_bf16.h>
#include <hip/hip_cooperative_groups.h>

namespace cg = cooperative_groups;

#define B_ 4
#define S_ 2048
#define E_ 1024
#define H_ 8
#define D_ 128

using f16x8 = __attribute__((ext_vector_type(8))) _Float16;
using f32x4 = __attribute__((ext_vector_type(4))) float;

__device__ __forceinline__ ushort f2h_bits(float f) {
    union { _Float16 h; ushort u; } cv; cv.h = (_Float16)f; return cv.u;
}
__device__ __forceinline__ f16x8 pack8(const float* __restrict__ p) {
    float4 f0 = *(const float4*)p;
    float4 f1 = *(const float4*)(p + 4);
    f16x8 r;
    r[0] = (_Float16)f0.x; r[1] = (_Float16)f0.y;
    r[2] = (_Float16)f0.z; r[3] = (_Float16)f0.w;
    r[4] = (_Float16)f1.x; r[5] = (_Float16)f1.y;
    r[6] = (_Float16)f1.z; r[7] = (_Float16)f1.w;
    return r;
}

// direct global->LDS DMA, 16B per lane; LDS dest is wave-uniform base + lane*16
__device__ __forceinline__ void gll16(const ushort* g, ushort* l) {
    __builtin_amdgcn_global_load_lds(
        (const __attribute__((address_space(1))) unsigned int*)g,
        (__attribute__((address_space(3))) unsigned int*)l, 16, 0, 0);
}

// ================== FUSED cooperative kernel ==================
// grid (S/128, H, B) = 512 blocks, block 512 (8 waves), LDS 80 KiB
// -> exactly 2 blocks/CU co-resident; __launch_bounds__(512,4) caps VGPR<=128.
// Phase A: this block projects K,V,Q for ITS 128 rows of (bi,h); seq A-frags
//   loaded once, reused for all three GEMMs. K/V stored pre-swizzled to ws.
// grid.sync()
// Phase B: R3 flash-attn loop verbatim (BN=64, DMA double-buffer, 1 barrier/iter).
__global__ __launch_bounds__(512, 4) void mha_fused(
    const float* __restrict__ seq,
    const float* __restrict__ Wq, const float* __restrict__ Wk,
    const float* __restrict__ Wv,
    const float* __restrict__ bq, const float* __restrict__ bk,
    const float* __restrict__ bv,
    ushort* __restrict__ ko, ushort* __restrict__ vo,
    float* __restrict__ out)
{
    __shared__ alignas(16) ushort smem[40960];       // 81920 B
    // phase A views
    ushort* const Tk = smem;                         // [128][136]
    ushort* const Tv = smem + 17408;                 // [128][136]
    ushort* const Qs = smem;                         // [128][128] (after stores)
    // phase B views
    ushort* const Kb0 = smem;                        // [64][128]
    ushort* const Kb1 = smem + 8192;
    ushort* const Vb0 = smem + 16384;                // [128][64]
    ushort* const Vb1 = smem + 24576;
    ushort* const Pbuf = smem + 32768;               // [128][64] P^T

    const int bx = blockIdx.x, h = blockIdx.y, bi = blockIdx.z;
    const int bh = bi * H_ + h;
    const int m0 = bx * 128;                         // row base within batch bi
    const int tid = threadIdx.x, lane = tid & 63, w = tid >> 6;
    const int l16 = lane & 15, quad = lane >> 4;
    const int swz = l16 & 7;
    const float qscale = 0.35355339059327373f * 1.4426950408889634f; // 1/sqrt(8)*log2e

    // ---------- Phase A: project K, V, Q for rows [m0, m0+128) ----------
    // A-frags: rows w*16 + l16 (same rows this wave owns in attn) — loaded ONCE
    f16x8 a[4];
    #pragma unroll
    for (int ks = 0; ks < 4; ++ks)
        a[ks] = pack8(&seq[((size_t)bi * S_ + m0 + w * 16 + l16) * E_
                           + h * D_ + ks * 32 + quad * 8]);

    // ---- K ----
    {
        const float* W = Wk + (size_t)h * D_ * D_;
        f32x4 acc[8];
        #pragma unroll
        for (int nt = 0; nt < 8; ++nt) { f32x4 z = {0.f,0.f,0.f,0.f}; acc[nt] = z; }
        #pragma unroll
        for (int ks = 0; ks < 4; ++ks)
            #pragma unroll
            for (int nt = 0; nt < 8; ++nt) {
                f16x8 bfr = pack8(&W[(size_t)(nt * 16 + l16) * D_ + ks * 32 + quad * 8]);
                acc[nt] = __builtin_amdgcn_mfma_f32_16x16x32_f16(
                    a[ks], bfr, acc[nt], 0, 0, 0);
            }
        #pragma unroll
        for (int nt = 0; nt < 8; ++nt) {
            int o = nt * 16 + l16;
            float bias = bk[h * D_ + o];
            #pragma unroll
            for (int r = 0; r < 4; ++r) {
                int row = w * 16 + quad * 4 + r;
                Tk[row * 136 + (o ^ (quad << 3))] = f2h_bits(acc[nt][r] + bias);
            }
        }
    }
    // ---- V ----
    {
        const float* W = Wv + (size_t)h * D_ * D_;
        f32x4 acc[8];
        #pragma unroll
        for (int nt = 0; nt < 8; ++nt) { f32x4 z = {0.f,0.f,0.f,0.f}; acc[nt] = z; }
        #pragma unroll
        for (int ks = 0; ks < 4; ++ks)
            #pragma unroll
            for (int nt = 0; nt < 8; ++nt) {
                f16x8 bfr = pack8(&W[(size_t)(nt * 16 + l16) * D_ + ks * 32 + quad * 8]);
                acc[nt] = __builtin_amdgcn_mfma_f32_16x16x32_f16(
                    a[ks], bfr, acc[nt], 0, 0, 0);
            }
        #pragma unroll
        for (int nt = 0; nt < 8; ++nt) {
            int o = nt * 16 + l16;
            float bias = bv[h * D_ + o];
            #pragma unroll
            for (int r = 0; r < 4; ++r) {
                int row = w * 16 + quad * 4 + r;     // s_local
                Tv[o * 136 + row] = f2h_bits(acc[nt][r] + bias);
            }
        }
    }
    __syncthreads();
    // ---- coalesced b128 stores to ws (attn pre-swizzle applied) ----
    #pragma unroll
    for (int i = 0; i < 4; ++i) {
        int idx = tid + i * 512;
        int row = idx >> 4, c8 = (idx & 15) * 8;
        int lk = c8 ^ ((row & 7) << 3);
        uint4 dk = *(uint4*)&Tk[row * 136 + (lk ^ (((row >> 2) & 3) << 3))];
        *(uint4*)&ko[((size_t)bh * S_ + m0 + row) * D_ + c8] = dk;
        uint4 dv = *(uint4*)&Tv[row * 136 + (c8 ^ ((row & 7) << 3))];
        *(uint4*)&vo[((size_t)bh * D_ + row) * S_ + m0 + c8] = dv;
    }
    __syncthreads();   // stores' LDS reads done; Qs may overwrite Tk region

    // ---- Q (reuses a[]) ----
    {
        const float* W = Wq + (size_t)h * D_ * D_;
        f32x4 qacc[8];
        #pragma unroll
        for (int nt = 0; nt < 8; ++nt) { f32x4 z = {0.f,0.f,0.f,0.f}; qacc[nt] = z; }
        #pragma unroll
        for (int ks = 0; ks < 4; ++ks)
            #pragma unroll
            for (int nt = 0; nt < 8; ++nt) {
                f16x8 bfr = pack8(&W[(size_t)(nt * 16 + l16) * D_ + ks * 32 + quad * 8]);
                qacc[nt] = __builtin_amdgcn_mfma_f32_16x16x32_f16(
                    a[ks], bfr, qacc[nt], 0, 0, 0);
            }
        #pragma unroll
        for (int nt = 0; nt < 8; ++nt) {
            int o = nt * 16 + l16;
            float bias = bq[h * D_ + o];
            #pragma unroll
            for (int r = 0; r < 4; ++r) {
                int row = w * 16 + quad * 4 + r;
                Qs[row * 128 + (o ^ (quad << 3))] =
                    f2h_bits((qacc[nt][r] + bias) * qscale);
            }
        }
    }
    // qf from own-wave rows (same-wave DS ordering suffices)
    f16x8 qf[4];
    #pragma unroll
    for (int ks = 0; ks < 4; ++ks)
        qf[ks] = *(const f16x8*)&Qs[(w * 16 + l16) * 128
                                    + ks * 32 + ((quad ^ (l16 >> 2)) << 3)];
    __syncthreads();

    // ---------- grid-wide sync: all blocks' K/V visible ----------
    cg::this_grid().sync();

    // ---------- Phase B: flash attention (R3 structure) ----------
    constexpr int NT = S_ / 64;                       // 32 K/V tiles
    const ushort* kbase = ko + (size_t)bh * S_ * D_;  // 64-row tile = 16 KB contiguous
    const ushort* vbase = vo + (size_t)bh * D_ * S_;  // row stride S_

    // DMA K0 + V0 (Qs content already in regs; overwrite OK)
    #pragma unroll
    for (int c = 0; c < 2; ++c) {
        int i = w * 2 + c;
        gll16(kbase + i * 512 + lane * 8, Kb0 + i * 512);
        gll16(vbase + (size_t)(i * 8 + (lane >> 3)) * S_ + (lane & 7) * 8,
              Vb0 + i * 512);
    }

    f32x4 o_acc[8];    // O^T: d = nt*16+quad*4+r, q = w*16+l16
    #pragma unroll
    for (int nt = 0; nt < 8; ++nt) { f32x4 z = {0.f,0.f,0.f,0.f}; o_acc[nt] = z; }
    float m_prev = -1e30f, l_lane = 0.f;

    __syncthreads();   // K0/V0 DMA drained

    ushort* const prow = &Pbuf[(w * 16 + l16) * 64];

    for (int j = 0; j < NT; ++j) {
        const ushort* KL = (j & 1) ? Kb1 : Kb0;
        const ushort* VL = (j & 1) ? Vb1 : Vb0;

        // prefetch tile j+1 (drains at this iter's end barrier)
        if (j + 1 < NT) {
            const ushort* kt = kbase + (size_t)(j + 1) * 64 * 128;
            const ushort* vt = vbase + (j + 1) * 64;
            ushort* kd = (j & 1) ? Kb0 : Kb1;
            ushort* vd = (j & 1) ? Vb0 : Vb1;
            #pragma unroll
            for (int c = 0; c < 2; ++c) {
                int i = w * 2 + c;
                gll16(kt + i * 512 + lane * 8, kd + i * 512);
                gll16(vt + (size_t)(i * 8 + (lane >> 3)) * S_ + (lane & 7) * 8,
                      vd + i * 512);
            }
        }

        // S^T = K Q^T: sacc[nt]: s = nt*16+quad*4+r, q = w*16+l16
        f32x4 sacc[4];
        #pragma unroll
        for (int nt = 0; nt < 4; ++nt) { f32x4 z = {0.f,0.f,0.f,0.f}; sacc[nt] = z; }
        __builtin_amdgcn_s_setprio(1);
        #pragma unroll
        for (int ks = 0; ks < 4; ++ks)
            #pragma unroll
            for (int nt = 0; nt < 4; ++nt) {
                f16x8 kf = *(const f16x8*)&KL[(nt * 16 + l16) * 128
                                              + (((ks * 4 + quad) ^ swz) << 3)];
                sacc[nt] = __builtin_amdgcn_mfma_f32_16x16x32_f16(
                    kf, qf[ks], sacc[nt], 0, 0, 0);
            }
        __builtin_amdgcn_s_setprio(0);

        // online softmax — 16 lane-local s-values
        uint2 pkw[4];
        {
            float mx = fmaxf(fmaxf(sacc[0][0], sacc[0][1]), fmaxf(sacc[0][2], sacc[0][3]));
            #pragma unroll
            for (int nt = 1; nt < 4; ++nt)
                mx = fmaxf(mx, fmaxf(fmaxf(sacc[nt][0], sacc[nt][1]),
                                     fmaxf(sacc[nt][2], sacc[nt][3])));
            mx = fmaxf(mx, __shfl_xor(mx, 16));
            mx = fmaxf(mx, __shfl_xor(mx, 32));
            // defer-max: rescale only when max grew past THR=8 (log2 domain, P<=256)
            if (__any(mx > m_prev + 8.0f)) {
                float mnew  = fmaxf(m_prev, mx);
                float alpha = exp2f(m_prev - mnew);
                #pragma unroll
                for (int nt = 0; nt < 8; ++nt)
                    #pragma unroll
                    for (int r = 0; r < 4; ++r) o_acc[nt][r] *= alpha;
                l_lane *= alpha;
                m_prev = mnew;
            }
            #pragma unroll
            for (int nt = 0; nt < 4; ++nt) {
                float e0 = exp2f(sacc[nt][0] - m_prev);
                float e1 = exp2f(sacc[nt][1] - m_prev);
                float e2 = exp2f(sacc[nt][2] - m_prev);
                float e3 = exp2f(sacc[nt][3] - m_prev);
                auto p01 = __builtin_amdgcn_cvt_pkrtz(e0, e1);
                auto p23 = __builtin_amdgcn_cvt_pkrtz(e2, e3);
                // denominator sees the same f16 quantization as the numerator
                l_lane += (float)p01[0] + (float)p01[1] + (float)p23[0] + (float)p23[1];
                pkw[nt] = make_uint2(__builtin_bit_cast(uint, p01),
                                     __builtin_bit_cast(uint, p23));
            }
        }

        // P^T[q][s] writes: b64 at 16B-group (2nt+(quad>>1))^swz, half quad&1
        #pragma unroll
        for (int nt = 0; nt < 4; ++nt) {
            int G = 2 * nt + (quad >> 1);
            *(uint2*)&prow[((G ^ swz) << 3) + ((quad & 1) << 2)] = pkw[nt];
        }

        // O^T += V^T P^T  (A = Vt frag, B = own-row P^T frag)
        __builtin_amdgcn_s_setprio(1);
        #pragma unroll
        for (int ks = 0; ks < 2; ++ks) {
            f16x8 pb = *(const f16x8*)&prow[((ks * 4 + quad) ^ swz) << 3];
            #pragma unroll
            for (int nt = 0; nt < 8; ++nt) {
                f16x8 vf = *(const f16x8*)&VL[(nt * 16 + l16) * 64
                                              + (((ks * 4 + quad) ^ swz) << 3)];
                o_acc[nt] = __builtin_amdgcn_mfma_f32_16x16x32_f16(
                    vf, pb, o_acc[nt], 0, 0, 0);
            }
        }
        __builtin_amdgcn_s_setprio(0);

        __syncthreads();   // reads of tile j done; tile j+1 DMA drained
    }

    // epilogue: complete l across quads, O/l, float4 stores to fp32 [B,S,E]
    {
        float l = l_lane;
        l += __shfl_xor(l, 16);
        l += __shfl_xor(l, 32);
        float rinv = 1.0f / l;
        const int q = m0 + w * 16 + l16;
        #pragma unroll
        for (int nt = 0; nt < 8; ++nt) {
            float4 o;
            o.x = o_acc[nt][0] * rinv;
            o.y = o_acc[nt][1] * rinv;
            o.z = o_acc[nt][2] * rinv;
            o.w = o_acc[nt][3] * rinv;
            *(float4*)&out[((size_t)bi * S_ + q) * E_ + h * D_ + nt * 16 + quad * 4] = o;
        }
    }
}

// ================== Fallback path (R2 kv_proj + R3 attn) ==================
__global__ __launch_bounds__(256) void kv_proj(
    const float* __restrict__ seq,
    const float* __restrict__ Wk, const float* __restrict__ Wv,
    const float* __restrict__ bk, const float* __restrict__ bv,
    ushort* __restrict__ ko, ushort* __restrict__ vo)
{
    constexpr int TS = 136;
    __shared__ ushort Tk[128 * TS];
    __shared__ ushort Tv[128 * TS];
    const int m0 = blockIdx.x * 128, h = blockIdx.y;
    const int tid = threadIdx.x, lane = tid & 63, w = tid >> 6;
    const int l16 = lane & 15, quad = lane >> 4;

    f16x8 a[2][4];
    #pragma unroll
    for (int mt = 0; mt < 2; ++mt)
        #pragma unroll
        for (int ks = 0; ks < 4; ++ks)
            a[mt][ks] = pack8(&seq[(size_t)(m0 + w * 32 + mt * 16 + l16) * E_
                                   + h * D_ + ks * 32 + quad * 8]);
    {
        const float* W = Wk + (size_t)h * D_ * D_;
        f32x4 acc[2][8];
        #pragma unroll
        for (int mt = 0; mt < 2; ++mt)
            #pragma unroll
            for (int nt = 0; nt < 8; ++nt) { f32x4 z = {0.f,0.f,0.f,0.f}; acc[mt][nt] = z; }
        #pragma unroll
        for (int ks = 0; ks < 4; ++ks)
            #pragma unroll
            for (int nt = 0; nt < 8; ++nt) {
                f16x8 bfr = pack8(&W[(size_t)(nt * 16 + l16) * D_ + ks * 32 + quad * 8]);
                #pragma unroll
                for (int mt = 0; mt < 2; ++mt)
                    acc[mt][nt] = __builtin_amdgcn_mfma_f32_16x16x32_f16(
                        a[mt][ks], bfr, acc[mt][nt], 0, 0, 0);
            }
        #pragma unroll
        for (int nt = 0; nt < 8; ++nt) {
            int o = nt * 16 + l16;
            float bias = bk[h * D_ + o];
            #pragma unroll
            for (int mt = 0; mt < 2; ++mt)
                #pragma unroll
                for (int r = 0; r < 4; ++r) {
                    int row = w * 32 + mt * 16 + quad * 4 + r;
                    Tk[row * TS + (o ^ (quad << 3))] = f2h_bits(acc[mt][nt][r] + bias);
                }
        }
    }
    {
        const float* W = Wv + (size_t)h * D_ * D_;
        f32x4 acc[2][8];
        #pragma unroll
        for (int mt = 0; mt < 2; ++mt)
            #pragma unroll
            for (int nt = 0; nt < 8; ++nt) { f32x4 z = {0.f,0.f,0.f,0.f}; acc[mt][nt] = z; }
        #pragma unroll
        for (int ks = 0; ks < 4; ++ks)
            #pragma unroll
            for (int nt = 0; nt < 8; ++nt) {
                f16x8 bfr = pack8(&W[(size_t)(nt * 16 + l16) * D_ + ks * 32 + quad * 8]);
                #pragma unroll
                for (int mt = 0; mt < 2; ++mt)
                    acc[mt][nt] = __builtin_amdgcn_mfma_f32_16x16x32_f16(
                        a[mt][ks], bfr, acc[mt][nt], 0, 0, 0);
            }
        #pragma unroll
        for (int nt = 0; nt < 8; ++nt) {
            int o = nt * 16 + l16;
            float bias = bv[h * D_ + o];
            #pragma unroll
            for (int mt = 0; mt < 2; ++mt)
                #pragma unroll
                for (int r = 0; r < 4; ++r) {
                    int row = w * 32 + mt * 16 + quad * 4 + r;
                    Tv[o * TS + row] = f2h_bits(acc[mt][nt][r] + bias);
                }
        }
    }
    __syncthreads();
    #pragma unroll
    for (int i = 0; i < 8; ++i) {
        int idx = tid + i * 256;
        int row = idx >> 4, c8 = (idx & 15) * 8;
        int lk = c8 ^ ((row & 7) << 3);
        uint4 dk = *(uint4*)&Tk[row * TS + (lk ^ (((row >> 2) & 3) << 3))];
        int m = m0 + row, bi = m >> 11, s = m & (S_ - 1);
        *(uint4*)&ko[(((size_t)bi * H_ + h) * S_ + s) * D_ + c8] = dk;
        uint4 dv = *(uint4*)&Tv[row * TS + (c8 ^ ((row & 7) << 3))];
        int mg = m0 + c8, bv_i = mg >> 11, s0 = mg & (S_ - 1);
        *(uint4*)&vo[(((size_t)bv_i * H_ + h) * D_ + row) * S_ + s0] = dv;
    }
}

__global__ __launch_bounds__(512) void attn(
    const float* __restrict__ seq, const float* __restrict__ Wq,
    const float* __restrict__ bq,
    const ushort* __restrict__ kg, const ushort* __restrict__ vtg,
    float* __restrict__ out)
{
    constexpr int NT = S_ / 64;
    __shared__ alignas(16) ushort Kbuf[2][64 * 128];
    __shared__ alignas(16) ushort Vbuf[2][128 * 64];
    __shared__ alignas(16) ushort Pbuf[128 * 64];

    const int m0 = blockIdx.x * 128;
    const int h = blockIdx.y, bi = blockIdx.z;
    const int bh = bi * H_ + h;
    const int tid = threadIdx.x, lane = tid & 63, w = tid >> 6;
    const int l16 = lane & 15, quad = lane >> 4;
    const int swz = l16 & 7;
    const ushort* kbase = kg + (size_t)bh * S_ * D_;
    const ushort* vbase = vtg + (size_t)bh * D_ * S_;
    const float qscale = 0.35355339059327373f * 1.4426950408889634f;

    #pragma unroll
    for (int c = 0; c < 2; ++c) {
        int i = w * 2 + c;
        gll16(vbase + (size_t)(i * 8 + (lane >> 3)) * S_ + (lane & 7) * 8,
              &Vbuf[0][0] + i * 512);
    }
    ushort* const Qs = &Kbuf[0][0];
    {
        f16x8 xa[4];
        #pragma unroll
        for (int ks = 0; ks < 4; ++ks)
            xa[ks] = pack8(&seq[((size_t)bi * S_ + m0 + w * 16 + l16) * E_
                                + h * D_ + ks * 32 + quad * 8]);
        f32x4 qacc[8];
        #pragma unroll
        for (int nt = 0; nt < 8; ++nt) { f32x4 z = {0.f,0.f,0.f,0.f}; qacc[nt] = z; }
        const float* W = Wq + (size_t)h * D_ * D_;
        #pragma unroll
        for (int ks = 0; ks < 4; ++ks)
            #pragma unroll
            for (int nt = 0; nt < 8; ++nt) {
                f16x8 bfr = pack8(&W[(size_t)(nt * 16 + l16) * D_ + ks * 32 + quad * 8]);
                qacc[nt] = __builtin_amdgcn_mfma_f32_16x16x32_f16(
                    xa[ks], bfr, qacc[nt], 0, 0, 0);
            }
        #pragma unroll
        for (int nt = 0; nt < 8; ++nt) {
            int o = nt * 16 + l16;
            float bias = bq[h * D_ + o];
            #pragma unroll
            for (int r = 0; r < 4; ++r) {
                int row = w * 16 + quad * 4 + r;
                Qs[row * 128 + (o ^ (quad << 3))] =
                    f2h_bits((qacc[nt][r] + bias) * qscale);
            }
        }
    }
    __syncthreads();
    f16x8 qf[4];
    #pragma unroll
    for (int ks = 0; ks < 4; ++ks)
        qf[ks] = *(const f16x8*)&Qs[(w * 16 + l16) * 128
                                    + ks * 32 + ((quad ^ (l16 >> 2)) << 3)];
    __syncthreads();
    #pragma unroll
    for (int c = 0; c < 2; ++c) {
        int i = w * 2 + c;
        gll16(kbase + i * 512 + lane * 8, &Kbuf[0][0] + i * 512);
    }
    f32x4 o_acc[8];
    #pragma unroll
    for (int nt = 0; nt < 8; ++nt) { f32x4 z = {0.f,0.f,0.f,0.f}; o_acc[nt] = z; }
    float m_prev = -1e30f, l_lane = 0.f;
    __syncthreads();

    ushort* const prow = &Pbuf[(w * 16 + l16) * 64];

    for (int j = 0; j < NT; ++j) {
        const int cur = j & 1;
        const ushort* KL = &Kbuf[cur][0];
        const ushort* VL = &Vbuf[cur][0];
        if (j + 1 < NT) {
            const ushort* kt = kbase + (size_t)(j + 1) * 64 * 128;
            const ushort* vt = vbase + (j + 1) * 64;
            ushort* kd = &Kbuf[cur ^ 1][0];
            ushort* vd = &Vbuf[cur ^ 1][0];
            #pragma unroll
            for (int c = 0; c < 2; ++c) {
                int i = w * 2 + c;
                gll16(kt + i * 512 + lane * 8, kd + i * 512);
                gll16(vt + (size_t)(i * 8 + (lane >> 3)) * S_ + (lane & 7) * 8,
                      vd + i * 512);
            }
        }
        f32x4 sacc[4];
        #pragma unroll
        for (int nt = 0; nt < 4; ++nt) { f32x4 z = {0.f,0.f,0.f,0.f}; sacc[nt] = z; }
        __builtin_amdgcn_s_setprio(1);
        #pragma unroll
        for (int ks = 0; ks < 4; ++ks)
            #pragma unroll
            for (int nt = 0; nt < 4; ++nt) {
                f16x8 kf = *(const f16x8*)&KL[(nt * 16 + l16) * 128
                                              + (((ks * 4 + quad) ^ swz) << 3)];
                sacc[nt] = __builtin_amdgcn_mfma_f32_16x16x32_f16(
                    kf, qf[ks], sacc[nt], 0, 0, 0);
            }
        __builtin_amdgcn_s_setprio(0);
        uint2 pkw[4];
        {
            float mx = fmaxf(fmaxf(sacc[0][0], sacc[0][1]), fmaxf(sacc[0][2], sacc[0][3]));
            #pragma unroll
            for (int nt = 1; nt < 4; ++nt)
                mx = fmaxf(mx, fmaxf(fmaxf(sacc[nt][0], sacc[nt][1]),
                                     fmaxf(sacc[nt][2], sacc[nt][3])));
            mx = fmaxf(mx, __shfl_xor(mx, 16));
            mx = fmaxf(mx, __shfl_xor(mx, 32));
            if (__any(mx > m_prev + 8.0f)) {
                float mnew  = fmaxf(m_prev, mx);
                float alpha = exp2f(m_prev - mnew);
                #pragma unroll
                for (int nt = 0; nt < 8; ++nt)
                    #pragma unroll
                    for (int r = 0; r < 4; ++r) o_acc[nt][r] *= alpha;
                l_lane *= alpha;
                m_prev = mnew;
            }
            #pragma unroll
            for (int nt = 0; nt < 4; ++nt) {
                float e0 = exp2f(sacc[nt][0] - m_prev);
                float e1 = exp2f(sacc[nt][1] - m_prev);
                float e2 = exp2f(sacc[nt][2] - m_prev);
                float e3 = exp2f(sacc[nt][3] - m_prev);
                auto p01 = __builtin_amdgcn_cvt_pkrtz(e0, e1);
                auto p23 = __builtin_amdgcn_cvt_pkrtz(e2, e3);
                l_lane += (float)p01[0] + (float)p01[1] + (float)p23[0] + (float)p23[1];
                pkw[nt] = make_uint2(__builtin_bit_cast(uint, p01),
                                     __builtin_bit_cast(uint, p23));
            }
        }
        #pragma unroll
        for (int nt = 0; nt < 4; ++nt) {
            int G = 2 * nt + (quad >> 1);
            *(uint2*)&prow[((G ^ swz) << 3) + ((quad & 1) << 2)] = pkw[nt];
        }
        __builtin_amdgcn_s_setprio(1);
        #pragma unroll
        for (int ks = 0; ks < 2; ++ks) {
            f16x8 pb = *(const f16x8*)&prow[((ks * 4 + quad) ^ swz) << 3];
            #pragma unroll
            for (int nt = 0; nt < 8; ++nt) {
                f16x8 vf = *(const f16x8*)&VL[(nt * 16 + l16) * 64
                                              + (((ks * 4 + quad) ^ swz) << 3)];
                o_acc[nt] = __builtin_amdgcn_mfma_f32_16x16x32_f16(
                    vf, pb, o_acc[nt], 0, 0, 0);
            }
        }
        __builtin_amdgcn_s_setprio(0);
        __syncthreads();
    }
    {
        float l = l_lane;
        l += __shfl_xor(l, 16);
        l += __shfl_xor(l, 32);
        float rinv = 1.0f / l;
        const int q = m0 + w * 16 + l16;
        #pragma unroll
        for (int nt = 0; nt < 8; ++nt) {
            float4 o;
            o.x = o_acc[nt][0] * rinv;
            o.y = o_acc[nt][1] * rinv;
            o.z = o_acc[nt][2] * rinv;
            o.w = o_acc[nt][3] * rinv;
            *(float4*)&out[((size_t)bi * S_ + q) * E_ + h * D_ + nt * 16 + quad * 4] = o;
        }
    }
}

extern "C" void kernel_launch(void* const* d_in, const int* in_sizes, int n_in,
                              void* d_out, int out_size, void* d_ws, size_t ws_size,
                              hipStream_t stream) {
    const float* seq = (const float*)d_in[0];
    const float* Wq  = (const float*)d_in[1];
    const float* Wk  = (const float*)d_in[2];
    const float* Wv  = (const float*)d_in[3];
    const float* bq  = (const float*)d_in[4];
    const float* bk  = (const float*)d_in[5];
    const float* bv  = (const float*)d_in[6];

    const size_t per = (size_t)B_ * H_ * S_ * D_;      // 8M elements
    if (ws_size < 2 * per * sizeof(ushort)) return;    // need 32 MB
    ushort* kws  = (ushort*)d_ws;          // [B,H,S,D]   pre-swizzled
    ushort* vtws = kws + per;              // [B,H,D,S]   pre-swizzled
    float* outp  = (float*)d_out;

    void* args[] = {(void*)&seq, (void*)&Wq, (void*)&Wk, (void*)&Wv,
                    (void*)&bq, (void*)&bk, (void*)&bv,
                    (void*)&kws, (void*)&vtws, (void*)&outp};
    hipError_t err = hipLaunchCooperativeKernel(
        (const void*)mha_fused, dim3(S_ / 128, H_, B_), dim3(512),
        args, 0, stream);
    if (err != hipSuccess) {
        // fallback: proven two-kernel path
        kv_proj<<<dim3(B_ * S_ / 128, H_), 256, 0, stream>>>(
            seq, Wk, Wv, bk, bv, kws, vtws);
        attn<<<dim3(S_ / 128, H_, B_), 512, 0, stream>>>(
            seq, Wq, bq, kws, vtws, outp);
    }
}

// Round 6
// 250.709 us; speedup vs baseline: 1.3247x; 1.3247x over previous
//
#include <hip/hip_runtime.h>
#include <hip/hip_bf16.h>

#define B_ 4
#define S_ 2048
#define E_ 1024
#define H_ 8
#define D_ 128

using f16x8 = __attribute__((ext_vector_type(8))) _Float16;
using f32x4 = __attribute__((ext_vector_type(4))) float;

__device__ __forceinline__ ushort f2h_bits(float f) {
    union { _Float16 h; ushort u; } cv; cv.h = (_Float16)f; return cv.u;
}
__device__ __forceinline__ f16x8 pack8(const float* __restrict__ p) {
    float4 f0 = *(const float4*)p;
    float4 f1 = *(const float4*)(p + 4);
    f16x8 r;
    r[0] = (_Float16)f0.x; r[1] = (_Float16)f0.y;
    r[2] = (_Float16)f0.z; r[3] = (_Float16)f0.w;
    r[4] = (_Float16)f1.x; r[5] = (_Float16)f1.y;
    r[6] = (_Float16)f1.z; r[7] = (_Float16)f1.w;
    return r;
}

// direct global->LDS DMA, 16B per lane; LDS dest is wave-uniform base + lane*16
__device__ __forceinline__ void gll16(const ushort* g, ushort* l) {
    __builtin_amdgcn_global_load_lds(
        (const __attribute__((address_space(1))) unsigned int*)g,
        (__attribute__((address_space(3))) unsigned int*)l, 16, 0, 0);
}

// ---------------- K/V projection (R2 version — fastest measured, ~15-20us) ----
// grid: (B*S/128, H), block 256.
// K out: [B,H,S,D] fp16, pre-swizzled: within each s-row, 8-elem chunk at
//   position p holds logical chunk p ^ (s&7).
// V out TRANSPOSED [B,H,D,S] fp16, pre-swizzled (64-block-local, 3-bit XOR):
//   position p holds logical chunk p ^ (d&7).
__global__ __launch_bounds__(256) void kv_proj(
    const float* __restrict__ seq,
    const float* __restrict__ Wk, const float* __restrict__ Wv,
    const float* __restrict__ bk, const float* __restrict__ bv,
    ushort* __restrict__ ko, ushort* __restrict__ vo)
{
    constexpr int TS = 136;
    __shared__ ushort Tk[128 * TS];   // [s_local][d]  (swizzled cols)
    __shared__ ushort Tv[128 * TS];   // [d][s_local]
    const int m0 = blockIdx.x * 128, h = blockIdx.y;
    const int tid = threadIdx.x, lane = tid & 63, w = tid >> 6;
    const int l16 = lane & 15, quad = lane >> 4;

    // A-frags: A[m=lane&15][k=quad*8+j]
    f16x8 a[2][4];
    #pragma unroll
    for (int mt = 0; mt < 2; ++mt)
        #pragma unroll
        for (int ks = 0; ks < 4; ++ks)
            a[mt][ks] = pack8(&seq[(size_t)(m0 + w * 32 + mt * 16 + l16) * E_
                                   + h * D_ + ks * 32 + quad * 8]);

    // ---- K ----
    {
        const float* W = Wk + (size_t)h * D_ * D_;
        f32x4 acc[2][8];
        #pragma unroll
        for (int mt = 0; mt < 2; ++mt)
            #pragma unroll
            for (int nt = 0; nt < 8; ++nt) { f32x4 z = {0.f,0.f,0.f,0.f}; acc[mt][nt] = z; }
        #pragma unroll
        for (int ks = 0; ks < 4; ++ks)
            #pragma unroll
            for (int nt = 0; nt < 8; ++nt) {
                f16x8 bfr = pack8(&W[(size_t)(nt * 16 + l16) * D_ + ks * 32 + quad * 8]);
                #pragma unroll
                for (int mt = 0; mt < 2; ++mt)
                    acc[mt][nt] = __builtin_amdgcn_mfma_f32_16x16x32_f16(
                        a[mt][ks], bfr, acc[mt][nt], 0, 0, 0);
            }
        #pragma unroll
        for (int nt = 0; nt < 8; ++nt) {
            int o = nt * 16 + l16;
            float bias = bk[h * D_ + o];
            #pragma unroll
            for (int mt = 0; mt < 2; ++mt)
                #pragma unroll
                for (int r = 0; r < 4; ++r) {
                    int row = w * 32 + mt * 16 + quad * 4 + r;
                    Tk[row * TS + (o ^ (quad << 3))] = f2h_bits(acc[mt][nt][r] + bias);
                }
        }
    }
    // ---- V ----
    {
        const float* W = Wv + (size_t)h * D_ * D_;
        f32x4 acc[2][8];
        #pragma unroll
        for (int mt = 0; mt < 2; ++mt)
            #pragma unroll
            for (int nt = 0; nt < 8; ++nt) { f32x4 z = {0.f,0.f,0.f,0.f}; acc[mt][nt] = z; }
        #pragma unroll
        for (int ks = 0; ks < 4; ++ks)
            #pragma unroll
            for (int nt = 0; nt < 8; ++nt) {
                f16x8 bfr = pack8(&W[(size_t)(nt * 16 + l16) * D_ + ks * 32 + quad * 8]);
                #pragma unroll
                for (int mt = 0; mt < 2; ++mt)
                    acc[mt][nt] = __builtin_amdgcn_mfma_f32_16x16x32_f16(
                        a[mt][ks], bfr, acc[mt][nt], 0, 0, 0);
            }
        #pragma unroll
        for (int nt = 0; nt < 8; ++nt) {
            int o = nt * 16 + l16;
            float bias = bv[h * D_ + o];
            #pragma unroll
            for (int mt = 0; mt < 2; ++mt)
                #pragma unroll
                for (int r = 0; r < 4; ++r) {
                    int row = w * 32 + mt * 16 + quad * 4 + r;
                    Tv[o * TS + row] = f2h_bits(acc[mt][nt][r] + bias);
                }
        }
    }
    __syncthreads();

    // coalesced b128 stores, applying the attn pre-swizzle
    #pragma unroll
    for (int i = 0; i < 8; ++i) {
        int idx = tid + i * 256;
        int row = idx >> 4, c8 = (idx & 15) * 8;
        // K: global position c8 holds LOGICAL chunk (c8 ^ ((row&7)<<3))
        int lk = c8 ^ ((row & 7) << 3);
        uint4 dk = *(uint4*)&Tk[row * TS + (lk ^ (((row >> 2) & 3) << 3))];
        int m = m0 + row, bi = m >> 11, s = m & (S_ - 1);
        *(uint4*)&ko[(((size_t)bi * H_ + h) * S_ + s) * D_ + c8] = dk;
        // V: position c8 holds logical s-chunk (c8 ^ ((d&7)<<3)), d = row
        uint4 dv = *(uint4*)&Tv[row * TS + (c8 ^ ((row & 7) << 3))];
        int mg = m0 + c8, bv_i = mg >> 11, s0 = mg & (S_ - 1);
        *(uint4*)&vo[(((size_t)bv_i * H_ + h) * D_ + row) * S_ + s0] = dv;
    }
}

// ---------------- Flash attention (R3 structure + XCD-grouping swizzle) ------
// grid: 512 blocks, block 512 (8 waves, 16 Q-rows each). BN = 64.
// XCD swizzle: linear block id L -> c=L&7 (XCD), t=L>>3; group g=c*4+(t&3)
// gives (h,bi); m0=(t>>2)*128. The 16 blocks sharing one (h,bi) K/V stream
// (2 MB) all have L%8==c -> same XCD -> tile sweep is L2-resident after the
// first toucher (bijective mapping; correctness-neutral).
// LDS = K[2][64x128] + V[2][128x64] + P[128x64] = 81920 B -> 2 blocks/CU
// (16 waves/CU, 4/SIMD). 1 barrier/iter; K,V double-buffered via
// global_load_lds DMA (prefetch j+1 at top of iter j, drained by the
// end-of-iter barrier). All swizzles XOR at 16B-chunk granularity.
__global__ __launch_bounds__(512) void attn(
    const float* __restrict__ seq, const float* __restrict__ Wq,
    const float* __restrict__ bq,
    const ushort* __restrict__ kg, const ushort* __restrict__ vtg,
    float* __restrict__ out)
{
    constexpr int NT = S_ / 64;
    __shared__ alignas(16) ushort Kbuf[2][64 * 128];
    __shared__ alignas(16) ushort Vbuf[2][128 * 64];
    __shared__ alignas(16) ushort Pbuf[128 * 64];

    // XCD-grouping block swizzle (bijection over 512 blocks)
    const int L = blockIdx.x + 16 * blockIdx.y + 128 * blockIdx.z;
    const int c = L & 7, t = L >> 3;
    const int g = c * 4 + (t & 3);         // 32 (h,bi) groups, 4 per XCD
    const int h = g & 7, bi = g >> 3;
    const int m0 = (t >> 2) * 128;

    const int bh = bi * H_ + h;
    const int tid = threadIdx.x, lane = tid & 63, w = tid >> 6;
    const int l16 = lane & 15, quad = lane >> 4;
    const int swz = l16 & 7;
    const ushort* kbase = kg + (size_t)bh * S_ * D_;   // 64-row tile = 16 KB contiguous
    const ushort* vbase = vtg + (size_t)bh * D_ * S_;  // row stride S_
    const float qscale = 0.35355339059327373f * 1.4426950408889634f; // 1/sqrt(8)*log2e

    // ---- prologue: DMA V tile 0 (Vbuf untouched by Q scratch) ----
    #pragma unroll
    for (int ci = 0; ci < 2; ++ci) {
        int i = w * 2 + ci;
        gll16(vbase + (size_t)(i * 8 + (lane >> 3)) * S_ + (lane & 7) * 8,
              &Vbuf[0][0] + i * 512);
    }

    // ---- Phase 0: Q tile = X Wq^T + bq (scaled), transposed through Kbuf ----
    ushort* const Qs = &Kbuf[0][0];                  // [128][128] scratch
    {
        f16x8 xa[4];
        #pragma unroll
        for (int ks = 0; ks < 4; ++ks)
            xa[ks] = pack8(&seq[((size_t)bi * S_ + m0 + w * 16 + l16) * E_
                                + h * D_ + ks * 32 + quad * 8]);
        f32x4 qacc[8];
        #pragma unroll
        for (int nt = 0; nt < 8; ++nt) { f32x4 z = {0.f,0.f,0.f,0.f}; qacc[nt] = z; }
        const float* W = Wq + (size_t)h * D_ * D_;
        #pragma unroll
        for (int ks = 0; ks < 4; ++ks)
            #pragma unroll
            for (int nt = 0; nt < 8; ++nt) {
                f16x8 bfr = pack8(&W[(size_t)(nt * 16 + l16) * D_ + ks * 32 + quad * 8]);
                qacc[nt] = __builtin_amdgcn_mfma_f32_16x16x32_f16(
                    xa[ks], bfr, qacc[nt], 0, 0, 0);
            }
        #pragma unroll
        for (int nt = 0; nt < 8; ++nt) {
            int o = nt * 16 + l16;
            float bias = bq[h * D_ + o];
            #pragma unroll
            for (int r = 0; r < 4; ++r) {
                int row = w * 16 + quad * 4 + r;
                Qs[row * 128 + (o ^ (quad << 3))] =
                    f2h_bits((qacc[nt][r] + bias) * qscale);
            }
        }
    }
    __syncthreads();   // Q visible (V0 DMA also drained)

    // qf[ks]: Q[q=w*16+l16][d=ks*32+quad*8..+7]
    f16x8 qf[4];
    #pragma unroll
    for (int ks = 0; ks < 4; ++ks)
        qf[ks] = *(const f16x8*)&Qs[(w * 16 + l16) * 128
                                    + ks * 32 + ((quad ^ (l16 >> 2)) << 3)];
    __syncthreads();   // all qf reads done before K0 DMA overwrites scratch

    // ---- DMA K tile 0 ----
    #pragma unroll
    for (int ci = 0; ci < 2; ++ci) {
        int i = w * 2 + ci;
        gll16(kbase + i * 512 + lane * 8, &Kbuf[0][0] + i * 512);
    }

    f32x4 o_acc[8];    // O^T: d = nt*16+quad*4+r, q = w*16+l16
    #pragma unroll
    for (int nt = 0; nt < 8; ++nt) { f32x4 z = {0.f,0.f,0.f,0.f}; o_acc[nt] = z; }
    float m_prev = -1e30f, l_lane = 0.f;

    __syncthreads();   // K0 drained

    ushort* const prow = &Pbuf[(w * 16 + l16) * 64];

    for (int j = 0; j < NT; ++j) {
        const int cur = j & 1;
        const ushort* KL = &Kbuf[cur][0];
        const ushort* VL = &Vbuf[cur][0];

        // prefetch tile j+1 (drains at this iter's end barrier)
        if (j + 1 < NT) {
            const ushort* kt = kbase + (size_t)(j + 1) * 64 * 128;
            const ushort* vt = vbase + (j + 1) * 64;
            ushort* kd = &Kbuf[cur ^ 1][0];
            ushort* vd = &Vbuf[cur ^ 1][0];
            #pragma unroll
            for (int ci = 0; ci < 2; ++ci) {
                int i = w * 2 + ci;
                gll16(kt + i * 512 + lane * 8, kd + i * 512);
                gll16(vt + (size_t)(i * 8 + (lane >> 3)) * S_ + (lane & 7) * 8,
                      vd + i * 512);
            }
        }

        // S^T = K Q^T: sacc[nt]: s = nt*16+quad*4+r, q = w*16+l16
        f32x4 sacc[4];
        #pragma unroll
        for (int nt = 0; nt < 4; ++nt) { f32x4 z = {0.f,0.f,0.f,0.f}; sacc[nt] = z; }
        __builtin_amdgcn_s_setprio(1);
        #pragma unroll
        for (int ks = 0; ks < 4; ++ks)
            #pragma unroll
            for (int nt = 0; nt < 4; ++nt) {
                f16x8 kf = *(const f16x8*)&KL[(nt * 16 + l16) * 128
                                              + (((ks * 4 + quad) ^ swz) << 3)];
                sacc[nt] = __builtin_amdgcn_mfma_f32_16x16x32_f16(
                    kf, qf[ks], sacc[nt], 0, 0, 0);
            }
        __builtin_amdgcn_s_setprio(0);

        // online softmax — 16 lane-local s-values
        uint2 pkw[4];
        {
            float mx = fmaxf(fmaxf(sacc[0][0], sacc[0][1]), fmaxf(sacc[0][2], sacc[0][3]));
            #pragma unroll
            for (int nt = 1; nt < 4; ++nt)
                mx = fmaxf(mx, fmaxf(fmaxf(sacc[nt][0], sacc[nt][1]),
                                     fmaxf(sacc[nt][2], sacc[nt][3])));
            mx = fmaxf(mx, __shfl_xor(mx, 16));
            mx = fmaxf(mx, __shfl_xor(mx, 32));
            // defer-max: rescale only when max grew past THR=8 (log2 domain, P<=256)
            if (__any(mx > m_prev + 8.0f)) {
                float mnew  = fmaxf(m_prev, mx);
                float alpha = exp2f(m_prev - mnew);
                #pragma unroll
                for (int nt = 0; nt < 8; ++nt)
                    #pragma unroll
                    for (int r = 0; r < 4; ++r) o_acc[nt][r] *= alpha;
                l_lane *= alpha;
                m_prev = mnew;
            }
            #pragma unroll
            for (int nt = 0; nt < 4; ++nt) {
                float e0 = exp2f(sacc[nt][0] - m_prev);
                float e1 = exp2f(sacc[nt][1] - m_prev);
                float e2 = exp2f(sacc[nt][2] - m_prev);
                float e3 = exp2f(sacc[nt][3] - m_prev);
                auto p01 = __builtin_amdgcn_cvt_pkrtz(e0, e1);
                auto p23 = __builtin_amdgcn_cvt_pkrtz(e2, e3);
                // denominator sees the same f16 quantization as the numerator
                l_lane += (float)p01[0] + (float)p01[1] + (float)p23[0] + (float)p23[1];
                pkw[nt] = make_uint2(__builtin_bit_cast(uint, p01),
                                     __builtin_bit_cast(uint, p23));
            }
        }

        // P^T[q][s] writes: b64 at 16B-group (2nt+(quad>>1))^swz, half quad&1
        #pragma unroll
        for (int nt = 0; nt < 4; ++nt) {
            int G = 2 * nt + (quad >> 1);
            *(uint2*)&prow[((G ^ swz) << 3) + ((quad & 1) << 2)] = pkw[nt];
        }

        // O^T += V^T P^T  (A = Vt frag, B = own-row P^T frag)
        __builtin_amdgcn_s_setprio(1);
        #pragma unroll
        for (int ks = 0; ks < 2; ++ks) {
            f16x8 pb = *(const f16x8*)&prow[((ks * 4 + quad) ^ swz) << 3];
            #pragma unroll
            for (int nt = 0; nt < 8; ++nt) {
                f16x8 vf = *(const f16x8*)&VL[(nt * 16 + l16) * 64
                                              + (((ks * 4 + quad) ^ swz) << 3)];
                o_acc[nt] = __builtin_amdgcn_mfma_f32_16x16x32_f16(
                    vf, pb, o_acc[nt], 0, 0, 0);
            }
        }
        __builtin_amdgcn_s_setprio(0);

        __syncthreads();   // reads of tile j done; tile j+1 DMA drained
    }

    // epilogue: complete l across quads, O/l, float4 stores to fp32 [B,S,E]
    {
        float l = l_lane;
        l += __shfl_xor(l, 16);
        l += __shfl_xor(l, 32);
        float rinv = 1.0f / l;
        const int q = m0 + w * 16 + l16;
        #pragma unroll
        for (int nt = 0; nt < 8; ++nt) {
            float4 o;
            o.x = o_acc[nt][0] * rinv;
            o.y = o_acc[nt][1] * rinv;
            o.z = o_acc[nt][2] * rinv;
            o.w = o_acc[nt][3] * rinv;
            *(float4*)&out[((size_t)bi * S_ + q) * E_ + h * D_ + nt * 16 + quad * 4] = o;
        }
    }
}

extern "C" void kernel_launch(void* const* d_in, const int* in_sizes, int n_in,
                              void* d_out, int out_size, void* d_ws, size_t ws_size,
                              hipStream_t stream) {
    const float* seq = (const float*)d_in[0];
    const float* Wq  = (const float*)d_in[1];
    const float* Wk  = (const float*)d_in[2];
    const float* Wv  = (const float*)d_in[3];
    const float* bq  = (const float*)d_in[4];
    const float* bk  = (const float*)d_in[5];
    const float* bv  = (const float*)d_in[6];

    const size_t per = (size_t)B_ * H_ * S_ * D_;      // 8M elements
    if (ws_size < 2 * per * sizeof(ushort)) return;    // need 32 MB
    ushort* kws  = (ushort*)d_ws;          // [B,H,S,D]   pre-swizzled
    ushort* vtws = kws + per;              // [B,H,D,S]   pre-swizzled

    kv_proj<<<dim3(B_ * S_ / 128, H_), 256, 0, stream>>>(
        seq, Wk, Wv, bk, bv, kws, vtws);
    attn<<<dim3(16, 8, 4), 512, 0, stream>>>(
        seq, Wq, bq, kws, vtws, (float*)d_out);
}

// Round 7
// 247.929 us; speedup vs baseline: 1.3396x; 1.0112x over previous
//
#include <hip/hip_runtime.h>
#include <hip/hip_bf16.h>

#define B_ 4
#define S_ 2048
#define E_ 1024
#define H_ 8
#define D_ 128

using f16x8 = __attribute__((ext_vector_type(8))) _Float16;
using f32x4 = __attribute__((ext_vector_type(4))) float;

__device__ __forceinline__ ushort f2h_bits(float f) {
    union { _Float16 h; ushort u; } cv; cv.h = (_Float16)f; return cv.u;
}
__device__ __forceinline__ float max3f(float a, float b, float c) {
    return fmaxf(fmaxf(a, b), c);     // clang fuses to v_max3_f32
}
__device__ __forceinline__ f16x8 pack8(const float* __restrict__ p) {
    float4 f0 = *(const float4*)p;
    float4 f1 = *(const float4*)(p + 4);
    f16x8 r;
    r[0] = (_Float16)f0.x; r[1] = (_Float16)f0.y;
    r[2] = (_Float16)f0.z; r[3] = (_Float16)f0.w;
    r[4] = (_Float16)f1.x; r[5] = (_Float16)f1.y;
    r[6] = (_Float16)f1.z; r[7] = (_Float16)f1.w;
    return r;
}

// direct global->LDS DMA, 16B per lane; LDS dest is wave-uniform base + lane*16
__device__ __forceinline__ void gll16(const ushort* g, ushort* l) {
    __builtin_amdgcn_global_load_lds(
        (const __attribute__((address_space(1))) unsigned int*)g,
        (__attribute__((address_space(3))) unsigned int*)l, 16, 0, 0);
}

// ---------------- K/V projection (R2 version — fastest measured, ~15-20us) ----
// grid: (B*S/128, H), block 256.
// K out: [B,H,S,D] fp16, pre-swizzled: within each s-row, 8-elem chunk at
//   position p holds logical chunk p ^ (s&7).
// V out TRANSPOSED [B,H,D,S] fp16, pre-swizzled (64-block-local, 3-bit XOR):
//   position p holds logical chunk p ^ (d&7).
__global__ __launch_bounds__(256) void kv_proj(
    const float* __restrict__ seq,
    const float* __restrict__ Wk, const float* __restrict__ Wv,
    const float* __restrict__ bk, const float* __restrict__ bv,
    ushort* __restrict__ ko, ushort* __restrict__ vo)
{
    constexpr int TS = 136;
    __shared__ ushort Tk[128 * TS];   // [s_local][d]  (swizzled cols)
    __shared__ ushort Tv[128 * TS];   // [d][s_local]
    const int m0 = blockIdx.x * 128, h = blockIdx.y;
    const int tid = threadIdx.x, lane = tid & 63, w = tid >> 6;
    const int l16 = lane & 15, quad = lane >> 4;

    // A-frags: A[m=lane&15][k=quad*8+j]
    f16x8 a[2][4];
    #pragma unroll
    for (int mt = 0; mt < 2; ++mt)
        #pragma unroll
        for (int ks = 0; ks < 4; ++ks)
            a[mt][ks] = pack8(&seq[(size_t)(m0 + w * 32 + mt * 16 + l16) * E_
                                   + h * D_ + ks * 32 + quad * 8]);

    // ---- K ----
    {
        const float* W = Wk + (size_t)h * D_ * D_;
        f32x4 acc[2][8];
        #pragma unroll
        for (int mt = 0; mt < 2; ++mt)
            #pragma unroll
            for (int nt = 0; nt < 8; ++nt) { f32x4 z = {0.f,0.f,0.f,0.f}; acc[mt][nt] = z; }
        #pragma unroll
        for (int ks = 0; ks < 4; ++ks)
            #pragma unroll
            for (int nt = 0; nt < 8; ++nt) {
                f16x8 bfr = pack8(&W[(size_t)(nt * 16 + l16) * D_ + ks * 32 + quad * 8]);
                #pragma unroll
                for (int mt = 0; mt < 2; ++mt)
                    acc[mt][nt] = __builtin_amdgcn_mfma_f32_16x16x32_f16(
                        a[mt][ks], bfr, acc[mt][nt], 0, 0, 0);
            }
        #pragma unroll
        for (int nt = 0; nt < 8; ++nt) {
            int o = nt * 16 + l16;
            float bias = bk[h * D_ + o];
            #pragma unroll
            for (int mt = 0; mt < 2; ++mt)
                #pragma unroll
                for (int r = 0; r < 4; ++r) {
                    int row = w * 32 + mt * 16 + quad * 4 + r;
                    Tk[row * TS + (o ^ (quad << 3))] = f2h_bits(acc[mt][nt][r] + bias);
                }
        }
    }
    // ---- V ----
    {
        const float* W = Wv + (size_t)h * D_ * D_;
        f32x4 acc[2][8];
        #pragma unroll
        for (int mt = 0; mt < 2; ++mt)
            #pragma unroll
            for (int nt = 0; nt < 8; ++nt) { f32x4 z = {0.f,0.f,0.f,0.f}; acc[mt][nt] = z; }
        #pragma unroll
        for (int ks = 0; ks < 4; ++ks)
            #pragma unroll
            for (int nt = 0; nt < 8; ++nt) {
                f16x8 bfr = pack8(&W[(size_t)(nt * 16 + l16) * D_ + ks * 32 + quad * 8]);
                #pragma unroll
                for (int mt = 0; mt < 2; ++mt)
                    acc[mt][nt] = __builtin_amdgcn_mfma_f32_16x16x32_f16(
                        a[mt][ks], bfr, acc[mt][nt], 0, 0, 0);
            }
        #pragma unroll
        for (int nt = 0; nt < 8; ++nt) {
            int o = nt * 16 + l16;
            float bias = bv[h * D_ + o];
            #pragma unroll
            for (int mt = 0; mt < 2; ++mt)
                #pragma unroll
                for (int r = 0; r < 4; ++r) {
                    int row = w * 32 + mt * 16 + quad * 4 + r;
                    Tv[o * TS + row] = f2h_bits(acc[mt][nt][r] + bias);
                }
        }
    }
    __syncthreads();

    // coalesced b128 stores, applying the attn pre-swizzle
    #pragma unroll
    for (int i = 0; i < 8; ++i) {
        int idx = tid + i * 256;
        int row = idx >> 4, c8 = (idx & 15) * 8;
        // K: global position c8 holds LOGICAL chunk (c8 ^ ((row&7)<<3))
        int lk = c8 ^ ((row & 7) << 3);
        uint4 dk = *(uint4*)&Tk[row * TS + (lk ^ (((row >> 2) & 3) << 3))];
        int m = m0 + row, bi = m >> 11, s = m & (S_ - 1);
        *(uint4*)&ko[(((size_t)bi * H_ + h) * S_ + s) * D_ + c8] = dk;
        // V: position c8 holds logical s-chunk (c8 ^ ((d&7)<<3)), d = row
        uint4 dv = *(uint4*)&Tv[row * TS + (c8 ^ ((row & 7) << 3))];
        int mg = m0 + c8, bv_i = mg >> 11, s0 = mg & (S_ - 1);
        *(uint4*)&vo[(((size_t)bv_i * H_ + h) * D_ + row) * S_ + s0] = dv;
    }
}

// ---------------- Flash attention (R6 + unroll-2 / max3 / early P-writes) ----
// grid: 512 blocks, block 512 (8 waves, 16 Q-rows each). BN = 64.
// XCD swizzle: linear block id L -> c=L&7 (XCD), t=L>>3; group g=c*4+(t&3)
// gives (h,bi); m0=(t>>2)*128 -> each (h,bi) K/V stream stays on one XCD's L2.
// LDS = K[2][64x128] + V[2][128x64] + P[128x64] = 81920 B -> 2 blocks/CU
// (16 waves/CU, 4/SIMD). 1 barrier/iter; K,V double-buffered via
// global_load_lds DMA (prefetch j+1 at top of iter j, drained by the
// end-of-iter barrier). Main loop unrolled x2 so the buffer parity is
// compile-time -> all 34 LDS vaddrs/iter are loop-invariant and hoisted
// (VGPR headroom: LDS caps occupancy at 4 waves/SIMD = 128 VGPR budget).
__global__ __launch_bounds__(512, 4) void attn(
    const float* __restrict__ seq, const float* __restrict__ Wq,
    const float* __restrict__ bq,
    const ushort* __restrict__ kg, const ushort* __restrict__ vtg,
    float* __restrict__ out)
{
    constexpr int NT = S_ / 64;
    __shared__ alignas(16) ushort Kbuf[2][64 * 128];
    __shared__ alignas(16) ushort Vbuf[2][128 * 64];
    __shared__ alignas(16) ushort Pbuf[128 * 64];

    // XCD-grouping block swizzle (bijection over 512 blocks)
    const int L = blockIdx.x + 16 * blockIdx.y + 128 * blockIdx.z;
    const int c = L & 7, t = L >> 3;
    const int g = c * 4 + (t & 3);         // 32 (h,bi) groups, 4 per XCD
    const int h = g & 7, bi = g >> 3;
    const int m0 = (t >> 2) * 128;

    const int bh = bi * H_ + h;
    const int tid = threadIdx.x, lane = tid & 63, w = tid >> 6;
    const int l16 = lane & 15, quad = lane >> 4;
    const int swz = l16 & 7;
    const ushort* kbase = kg + (size_t)bh * S_ * D_;   // 64-row tile = 16 KB contiguous
    const ushort* vbase = vtg + (size_t)bh * D_ * S_;  // row stride S_
    const float qscale = 0.35355339059327373f * 1.4426950408889634f; // 1/sqrt(8)*log2e

    // ---- prologue: DMA V tile 0 (Vbuf untouched by Q scratch) ----
    #pragma unroll
    for (int ci = 0; ci < 2; ++ci) {
        int i = w * 2 + ci;
        gll16(vbase + (size_t)(i * 8 + (lane >> 3)) * S_ + (lane & 7) * 8,
              &Vbuf[0][0] + i * 512);
    }

    // ---- Phase 0: Q tile = X Wq^T + bq (scaled), transposed through Kbuf ----
    ushort* const Qs = &Kbuf[0][0];                  // [128][128] scratch
    {
        f16x8 xa[4];
        #pragma unroll
        for (int ks = 0; ks < 4; ++ks)
            xa[ks] = pack8(&seq[((size_t)bi * S_ + m0 + w * 16 + l16) * E_
                                + h * D_ + ks * 32 + quad * 8]);
        f32x4 qacc[8];
        #pragma unroll
        for (int nt = 0; nt < 8; ++nt) { f32x4 z = {0.f,0.f,0.f,0.f}; qacc[nt] = z; }
        const float* W = Wq + (size_t)h * D_ * D_;
        #pragma unroll
        for (int ks = 0; ks < 4; ++ks)
            #pragma unroll
            for (int nt = 0; nt < 8; ++nt) {
                f16x8 bfr = pack8(&W[(size_t)(nt * 16 + l16) * D_ + ks * 32 + quad * 8]);
                qacc[nt] = __builtin_amdgcn_mfma_f32_16x16x32_f16(
                    xa[ks], bfr, qacc[nt], 0, 0, 0);
            }
        #pragma unroll
        for (int nt = 0; nt < 8; ++nt) {
            int o = nt * 16 + l16;
            float bias = bq[h * D_ + o];
            #pragma unroll
            for (int r = 0; r < 4; ++r) {
                int row = w * 16 + quad * 4 + r;
                Qs[row * 128 + (o ^ (quad << 3))] =
                    f2h_bits((qacc[nt][r] + bias) * qscale);
            }
        }
    }
    __syncthreads();   // Q visible (V0 DMA also drained)

    // qf[ks]: Q[q=w*16+l16][d=ks*32+quad*8..+7]
    f16x8 qf[4];
    #pragma unroll
    for (int ks = 0; ks < 4; ++ks)
        qf[ks] = *(const f16x8*)&Qs[(w * 16 + l16) * 128
                                    + ks * 32 + ((quad ^ (l16 >> 2)) << 3)];
    __syncthreads();   // all qf reads done before K0 DMA overwrites scratch

    // ---- DMA K tile 0 ----
    #pragma unroll
    for (int ci = 0; ci < 2; ++ci) {
        int i = w * 2 + ci;
        gll16(kbase + i * 512 + lane * 8, &Kbuf[0][0] + i * 512);
    }

    f32x4 o_acc[8];    // O^T: d = nt*16+quad*4+r, q = w*16+l16
    #pragma unroll
    for (int nt = 0; nt < 8; ++nt) { f32x4 z = {0.f,0.f,0.f,0.f}; o_acc[nt] = z; }
    float m_prev = -1e30f, l_lane = 0.f;

    __syncthreads();   // K0 drained

    ushort* const prow = &Pbuf[(w * 16 + l16) * 64];

    #pragma unroll 2   // folds (j&1) -> compile-time buffer parity
    for (int j = 0; j < NT; ++j) {
        const int cur = j & 1;
        const ushort* KL = &Kbuf[cur][0];
        const ushort* VL = &Vbuf[cur][0];

        // prefetch tile j+1 (drains at this iter's end barrier)
        if (j + 1 < NT) {
            const ushort* kt = kbase + (size_t)(j + 1) * 64 * 128;
            const ushort* vt = vbase + (j + 1) * 64;
            ushort* kd = &Kbuf[cur ^ 1][0];
            ushort* vd = &Vbuf[cur ^ 1][0];
            #pragma unroll
            for (int ci = 0; ci < 2; ++ci) {
                int i = w * 2 + ci;
                gll16(kt + i * 512 + lane * 8, kd + i * 512);
                gll16(vt + (size_t)(i * 8 + (lane >> 3)) * S_ + (lane & 7) * 8,
                      vd + i * 512);
            }
        }

        // S^T = K Q^T: sacc[nt]: s = nt*16+quad*4+r, q = w*16+l16
        f32x4 sacc[4];
        #pragma unroll
        for (int nt = 0; nt < 4; ++nt) { f32x4 z = {0.f,0.f,0.f,0.f}; sacc[nt] = z; }
        __builtin_amdgcn_s_setprio(1);
        #pragma unroll
        for (int ks = 0; ks < 4; ++ks)
            #pragma unroll
            for (int nt = 0; nt < 4; ++nt) {
                f16x8 kf = *(const f16x8*)&KL[(nt * 16 + l16) * 128
                                              + (((ks * 4 + quad) ^ swz) << 3)];
                sacc[nt] = __builtin_amdgcn_mfma_f32_16x16x32_f16(
                    kf, qf[ks], sacc[nt], 0, 0, 0);
            }
        __builtin_amdgcn_s_setprio(0);

        // online softmax — 16 lane-local s-values; max tree in v_max3 shape
        {
            float v0 = max3f(sacc[0][0], sacc[0][1], sacc[0][2]);
            float v1 = max3f(sacc[0][3], sacc[1][0], sacc[1][1]);
            float v2 = max3f(sacc[1][2], sacc[1][3], sacc[2][0]);
            float v3 = max3f(sacc[2][1], sacc[2][2], sacc[2][3]);
            float v4 = max3f(sacc[3][0], sacc[3][1], sacc[3][2]);
            float mx = fmaxf(max3f(v0, v1, v2), max3f(v3, v4, sacc[3][3]));
            mx = fmaxf(mx, __shfl_xor(mx, 16));
            mx = fmaxf(mx, __shfl_xor(mx, 32));
            // defer-max: rescale only when max grew past THR=8 (log2 domain, P<=256)
            if (__any(mx > m_prev + 8.0f)) {
                float mnew  = fmaxf(m_prev, mx);
                float alpha = exp2f(m_prev - mnew);
                #pragma unroll
                for (int nt = 0; nt < 8; ++nt)
                    #pragma unroll
                    for (int r = 0; r < 4; ++r) o_acc[nt][r] *= alpha;
                l_lane *= alpha;
                m_prev = mnew;
            }
            #pragma unroll
            for (int nt = 0; nt < 4; ++nt) {
                float e0 = exp2f(sacc[nt][0] - m_prev);
                float e1 = exp2f(sacc[nt][1] - m_prev);
                float e2 = exp2f(sacc[nt][2] - m_prev);
                float e3 = exp2f(sacc[nt][3] - m_prev);
                auto p01 = __builtin_amdgcn_cvt_pkrtz(e0, e1);
                auto p23 = __builtin_amdgcn_cvt_pkrtz(e2, e3);
                // early P^T write: overlaps ds_write with next nt's exp work
                int G = 2 * nt + (quad >> 1);
                *(uint2*)&prow[((G ^ swz) << 3) + ((quad & 1) << 2)] =
                    make_uint2(__builtin_bit_cast(uint, p01),
                               __builtin_bit_cast(uint, p23));
                // denominator sees the same f16 quantization as the numerator
                l_lane += (float)p01[0] + (float)p01[1] + (float)p23[0] + (float)p23[1];
            }
        }

        // O^T += V^T P^T  (A = Vt frag, B = own-row P^T frag)
        __builtin_amdgcn_s_setprio(1);
        #pragma unroll
        for (int ks = 0; ks < 2; ++ks) {
            f16x8 pb = *(const f16x8*)&prow[((ks * 4 + quad) ^ swz) << 3];
            #pragma unroll
            for (int nt = 0; nt < 8; ++nt) {
                f16x8 vf = *(const f16x8*)&VL[(nt * 16 + l16) * 64
                                              + (((ks * 4 + quad) ^ swz) << 3)];
                o_acc[nt] = __builtin_amdgcn_mfma_f32_16x16x32_f16(
                    vf, pb, o_acc[nt], 0, 0, 0);
            }
        }
        __builtin_amdgcn_s_setprio(0);

        __syncthreads();   // reads of tile j done; tile j+1 DMA drained
    }

    // epilogue: complete l across quads, O/l, float4 stores to fp32 [B,S,E]
    {
        float l = l_lane;
        l += __shfl_xor(l, 16);
        l += __shfl_xor(l, 32);
        float rinv = 1.0f / l;
        const int q = m0 + w * 16 + l16;
        #pragma unroll
        for (int nt = 0; nt < 8; ++nt) {
            float4 o;
            o.x = o_acc[nt][0] * rinv;
            o.y = o_acc[nt][1] * rinv;
            o.z = o_acc[nt][2] * rinv;
            o.w = o_acc[nt][3] * rinv;
            *(float4*)&out[((size_t)bi * S_ + q) * E_ + h * D_ + nt * 16 + quad * 4] = o;
        }
    }
}

extern "C" void kernel_launch(void* const* d_in, const int* in_sizes, int n_in,
                              void* d_out, int out_size, void* d_ws, size_t ws_size,
                              hipStream_t stream) {
    const float* seq = (const float*)d_in[0];
    const float* Wq  = (const float*)d_in[1];
    const float* Wk  = (const float*)d_in[2];
    const float* Wv  = (const float*)d_in[3];
    const float* bq  = (const float*)d_in[4];
    const float* bk  = (const float*)d_in[5];
    const float* bv  = (const float*)d_in[6];

    const size_t per = (size_t)B_ * H_ * S_ * D_;      // 8M elements
    if (ws_size < 2 * per * sizeof(ushort)) return;    // need 32 MB
    ushort* kws  = (ushort*)d_ws;          // [B,H,S,D]   pre-swizzled
    ushort* vtws = kws + per;              // [B,H,D,S]   pre-swizzled

    kv_proj<<<dim3(B_ * S_ / 128, H_), 256, 0, stream>>>(
        seq, Wk, Wv, bk, bv, kws, vtws);
    attn<<<dim3(16, 8, 4), 512, 0, stream>>>(
        seq, Wq, bq, kws, vtws, (float*)d_out);
}